// Round 6
// baseline (702.346 us; speedup 1.0000x reference)
//
#include <hip/hip_runtime.h>
#include <math.h>

#define NLEVELS 16
#define TBLSIZE 524288u   // power of two -> mod == mask
#define NPTS    524288
#define OUT_ENC_ELEMS (NPTS * NLEVELS * 2)  // 16777216 floats, then tv

typedef float f32x2 __attribute__((ext_vector_type(2)));

struct LevelMeta {
    float scale[NLEVELS];
    unsigned int res[NLEVELS];
    unsigned int off[NLEVELS];   // entry offset of each level's table
    unsigned int fhl;            // first hash level
};

__global__ __launch_bounds__(256) void hashgrid_encode_kernel(
    const float* __restrict__ pos,
    const float* __restrict__ latents,
    const float* __restrict__ bound_p,
    float* __restrict__ out,
    LevelMeta meta)
{
    const unsigned int tid = blockIdx.x * blockDim.x + threadIdx.x;
    const unsigned int level = tid & (NLEVELS - 1);
    const unsigned int point = tid >> 4;
    if (point >= NPTS) return;

    const float bound = bound_p[0];
    const float denom = 2.0f * bound;

    // posn = (pos + bound) / (2*bound)  — correctly-rounded div, matches JAX
    const float px = (pos[point * 3 + 0] + bound) / denom;
    const float py = (pos[point * 3 + 1] + bound) / denom;
    const float pz = (pos[point * 3 + 2] + bound) / denom;

    // pos_scaled = posn*scale + 0.5 with SEPARATE rounding (no FMA contraction)
    // to match the reference's two-op computation bit-for-bit; floor() is
    // discontinuous so contraction here could flip the selected cell.
    const float scale = meta.scale[level];
    const float sx = __fadd_rn(__fmul_rn(px, scale), 0.5f);
    const float sy = __fadd_rn(__fmul_rn(py, scale), 0.5f);
    const float sz = __fadd_rn(__fmul_rn(pz, scale), 0.5f);

    const float fx = floorf(sx);
    const float fy = floorf(sy);
    const float fz = floorf(sz);

    const float ox = __fsub_rn(sx, fx);   // pos_off in [0,1)
    const float oy = __fsub_rn(sy, fy);
    const float oz = __fsub_rn(sz, fz);

    const unsigned int bx = (unsigned int)fx;
    const unsigned int by = (unsigned int)fy;
    const unsigned int bz = (unsigned int)fz;

    const unsigned int res = meta.res[level];
    const unsigned int off = meta.off[level];
    const bool hashed = (level >= meta.fhl);

    const unsigned int p1 = 2654435761u;
    const unsigned int p2 = 805459861u;

    const f32x2* __restrict__ lat2 = (const f32x2*)latents;

    float acc0 = 0.0f;
    float acc1 = 0.0f;

#pragma unroll
    for (int c = 0; c < 8; ++c) {
        const unsigned int c0 = (c >> 2) & 1;  // dim 0 offset
        const unsigned int c1 = (c >> 1) & 1;  // dim 1
        const unsigned int c2 = c & 1;         // dim 2
        const unsigned int vx = bx + c0;
        const unsigned int vy = by + c1;
        const unsigned int vz = bz + c2;

        unsigned int idx_t = vx + vy * res + vz * res * res;
        unsigned int idx_h = vx ^ (vy * p1) ^ (vz * p2);
        unsigned int idx = (hashed ? idx_h : idx_t) & (TBLSIZE - 1u);
        idx += off;

        const float wx = c0 ? ox : (1.0f - ox);
        const float wy = c1 ? oy : (1.0f - oy);
        const float wz = c2 ? oz : (1.0f - oz);
        const float w = wx * wy * wz;

        const f32x2 v = lat2[idx];
        acc0 += v.x * w;
        acc1 += v.y * w;
    }

    // out layout: enc[point][level*2 + f] — consecutive lanes (same point's
    // group of 16 levels) write contiguous 8B chunks -> coalesced 512B/wave.
    // Non-temporal: output is write-once; keep L2 for the latent tables.
    f32x2* __restrict__ o2 = (f32x2*)out;
    f32x2 res2;
    res2.x = acc0;
    res2.y = acc1;
    __builtin_nontemporal_store(res2, &o2[point * NLEVELS + level]);

    if (tid == 0) {
        out[OUT_ENC_ELEMS] = 0.0f;  // tv
    }
}

extern "C" void kernel_launch(void* const* d_in, const int* in_sizes, int n_in,
                              void* d_out, int out_size, void* d_ws, size_t ws_size,
                              hipStream_t stream) {
    const float* pos     = (const float*)d_in[0];
    const float* latents = (const float*)d_in[1];
    const float* bound_p = (const float*)d_in[2];
    float* out = (float*)d_out;

    // Replicate grid_meta() exactly in double precision.
    LevelMeta meta;
    const double b = exp((log(2048.0) - log(16.0)) / 15.0);
    unsigned int off = 0;
    unsigned int fhl = 0;
    for (int i = 0; i < NLEVELS; ++i) {
        const double scale = 16.0 * pow(b, (double)i) - 1.0;
        meta.scale[i] = (float)scale;
        const unsigned int res = (unsigned int)ceil(scale) + 1u;
        meta.res[i] = res;
        unsigned int n_entries = res * res * res;
        if (n_entries <= TBLSIZE) {
            fhl = (unsigned int)(i + 1);
        } else {
            n_entries = TBLSIZE;
        }
        meta.off[i] = off;
        off += n_entries;
    }
    meta.fhl = fhl;

    const int total_threads = NPTS * NLEVELS;
    const int block = 256;
    const int grid = (total_threads + block - 1) / block;
    hipLaunchKernelGGL(hashgrid_encode_kernel, dim3(grid), dim3(block), 0, stream,
                       pos, latents, bound_p, out, meta);
}

// Round 7
// 506.395 us; speedup vs baseline: 1.3870x; 1.3870x over previous
//
#include <hip/hip_runtime.h>
#include <math.h>

#define NLEVELS 16
#define TBLSIZE 524288u   // power of two -> mod == mask
#define NPTS    524288
#define OUT_ENC_ELEMS (NPTS * NLEVELS * 2)  // 16777216 floats, then tv

typedef float f32x2 __attribute__((ext_vector_type(2)));
typedef float f32x4 __attribute__((ext_vector_type(4)));

struct LevelMeta {
    float scale[NLEVELS];
    unsigned int res[NLEVELS];
    unsigned int off[NLEVELS];   // entry offset of each level's table
    unsigned int fhl;            // first hash level
};

// One thread per point; loop levels 0..15 IN ORDER so the whole GPU sweeps
// one ~4MB table at a time (L2-resident per XCD), instead of mixing all 16
// tables (48.8MB) in every block's working set, which thrashed L2
// (FETCH_SIZE 2.2GB, round-6 counters).
__global__ __launch_bounds__(256, 4) void hashgrid_encode_kernel(
    const float* __restrict__ pos,
    const float* __restrict__ latents,
    const float* __restrict__ bound_p,
    float* __restrict__ out,
    LevelMeta meta)
{
    const unsigned int point = blockIdx.x * 256u + threadIdx.x;   // NPTS % 256 == 0

    const float bound = bound_p[0];
    const float denom = 2.0f * bound;

    // posn = (pos + bound) / (2*bound) — correctly-rounded, matches JAX
    const float px = (pos[point * 3 + 0] + bound) / denom;
    const float py = (pos[point * 3 + 1] + bound) / denom;
    const float pz = (pos[point * 3 + 2] + bound) / denom;

    const unsigned int p1 = 2654435761u;
    const unsigned int p2 = 805459861u;
    const f32x2* __restrict__ lat2 = (const f32x2*)latents;

    f32x2 acc[NLEVELS];   // unrolled loop -> static indices -> registers

#pragma unroll
    for (int l = 0; l < NLEVELS; ++l) {
        const float scale = meta.scale[l];
        const unsigned int res = meta.res[l];
        const unsigned int off = meta.off[l];
        const bool hashed = ((unsigned int)l >= meta.fhl);

        // pos_scaled = posn*scale + 0.5 with SEPARATE rounding (no FMA
        // contraction): floor() is discontinuous, contraction could flip cells.
        const float sx = __fadd_rn(__fmul_rn(px, scale), 0.5f);
        const float sy = __fadd_rn(__fmul_rn(py, scale), 0.5f);
        const float sz = __fadd_rn(__fmul_rn(pz, scale), 0.5f);

        const float fx = floorf(sx);
        const float fy = floorf(sy);
        const float fz = floorf(sz);

        const float ox = __fsub_rn(sx, fx);
        const float oy = __fsub_rn(sy, fy);
        const float oz = __fsub_rn(sz, fz);

        const unsigned int bx = (unsigned int)fx;
        const unsigned int by = (unsigned int)fy;
        const unsigned int bz = (unsigned int)fz;

        float acc0 = 0.0f;
        float acc1 = 0.0f;

#pragma unroll
        for (int c = 0; c < 8; ++c) {
            const unsigned int c0 = (c >> 2) & 1;
            const unsigned int c1 = (c >> 1) & 1;
            const unsigned int c2 = c & 1;
            const unsigned int vx = bx + c0;
            const unsigned int vy = by + c1;
            const unsigned int vz = bz + c2;

            unsigned int idx_t = vx + vy * res + vz * res * res;
            unsigned int idx_h = vx ^ (vy * p1) ^ (vz * p2);
            unsigned int idx = (hashed ? idx_h : idx_t) & (TBLSIZE - 1u);
            idx += off;

            const float wx = c0 ? ox : (1.0f - ox);
            const float wy = c1 ? oy : (1.0f - oy);
            const float wz = c2 ? oz : (1.0f - oz);
            const float w = wx * wy * wz;

            const f32x2 v = lat2[idx];
            acc0 += v.x * w;
            acc1 += v.y * w;
        }

        acc[l].x = acc0;
        acc[l].y = acc1;

        // Keep the sweep tight: align the block's waves to the same level and
        // forbid the compiler from hoisting the next level's gathers into
        // this one (which would put 2-3 tables in flight and re-thrash L2).
        __syncthreads();
        __builtin_amdgcn_sched_barrier(0);
    }

    // Each thread owns one point's full 128B output row -> the wave writes a
    // contiguous 8KB region; L2 merges the 16B strided sectors into full lines.
    // Non-temporal: write-once output, keep L2 for the tables.
    f32x4* __restrict__ o4 = (f32x4*)(out + (size_t)point * (NLEVELS * 2));
#pragma unroll
    for (int i = 0; i < 8; ++i) {
        f32x4 v;
        v.x = acc[2 * i].x;
        v.y = acc[2 * i].y;
        v.z = acc[2 * i + 1].x;
        v.w = acc[2 * i + 1].y;
        __builtin_nontemporal_store(v, &o4[i]);
    }

    if (point == 0) {
        out[OUT_ENC_ELEMS] = 0.0f;  // tv
    }
}

extern "C" void kernel_launch(void* const* d_in, const int* in_sizes, int n_in,
                              void* d_out, int out_size, void* d_ws, size_t ws_size,
                              hipStream_t stream) {
    const float* pos     = (const float*)d_in[0];
    const float* latents = (const float*)d_in[1];
    const float* bound_p = (const float*)d_in[2];
    float* out = (float*)d_out;

    // Replicate grid_meta() exactly in double precision.
    LevelMeta meta;
    const double b = exp((log(2048.0) - log(16.0)) / 15.0);
    unsigned int off = 0;
    unsigned int fhl = 0;
    for (int i = 0; i < NLEVELS; ++i) {
        const double scale = 16.0 * pow(b, (double)i) - 1.0;
        meta.scale[i] = (float)scale;
        const unsigned int res = (unsigned int)ceil(scale) + 1u;
        meta.res[i] = res;
        unsigned int n_entries = res * res * res;
        if (n_entries <= TBLSIZE) {
            fhl = (unsigned int)(i + 1);
        } else {
            n_entries = TBLSIZE;
        }
        meta.off[i] = off;
        off += n_entries;
    }
    meta.fhl = fhl;

    const int block = 256;
    const int grid = NPTS / block;   // 2048 blocks, one thread per point
    hipLaunchKernelGGL(hashgrid_encode_kernel, dim3(grid), dim3(block), 0, stream,
                       pos, latents, bound_p, out, meta);
}